// Round 5
// baseline (18809.425 us; speedup 1.0000x reference)
//
#include <hip/hip_runtime.h>

typedef unsigned short u16;
typedef unsigned int   u32;

// sizes: B=16, L=256, D=256, H=256, E=256, V=172, T=128
// inputs: f32 (runtime-verified); output: f32 (harness maps f32 reference output -> float*)
// ws layout (12,582,912 bytes); every byte written before read, no init needed
#define OFF_ENCP 0ull          // u16 [16][256][256]  enc_proj, bf16
#define OFF_GY   2097152ull    // f32 [128][16][1024] emb-part of gates + biases
#define OFF_OALL 10485760ull   // f32 [128][16][256]  o_t per step

__device__ __forceinline__ float b2f(u32 lo16){ u32 x = lo16 << 16; float f; __builtin_memcpy(&f,&x,4); return f; }
__device__ __forceinline__ u16 f2b(float f){ u32 x; __builtin_memcpy(&x,&f,4); x = x + 0x7fffu + ((x>>16)&1u); return (u16)(x>>16); }
__device__ __forceinline__ float sigm(float x){ return 1.0f/(1.0f+__expf(-x)); }
__device__ __forceinline__ float tanh_f(float x){ return 1.0f - 2.0f/(1.0f+__expf(2.0f*x)); }

// runtime dtype detect (safety net): bf16-packed words have a bf16 exponent at bits 7..14
__device__ __forceinline__ int detect_f32(const void* imgs){
  const u32* W = (const u32*)imgs;
  int c2 = 0;
  for (int k=0; k<64; k++){
    u32 e = (W[k] >> 7) & 0xFFu;
    if (e >= 100u && e <= 132u) c2++;     // N(0,1) bf16 always hits; f32 mantissa ~13%
  }
  return (c2 < 36) ? 1 : 0;
}

struct F8 { float v[8]; };
__device__ __forceinline__ F8 ld8(const void* p, size_t i, bool f32){
  F8 r;
  if (f32){
    const float* q = (const float*)p + i;
    float4 a = *(const float4*)q; float4 b = *(const float4*)(q+4);
    r.v[0]=a.x;r.v[1]=a.y;r.v[2]=a.z;r.v[3]=a.w;r.v[4]=b.x;r.v[5]=b.y;r.v[6]=b.z;r.v[7]=b.w;
  } else {
    uint4 q = *(const uint4*)((const u16*)p + i);
    r.v[0]=b2f(q.x&0xffffu); r.v[1]=b2f(q.x>>16);
    r.v[2]=b2f(q.y&0xffffu); r.v[3]=b2f(q.y>>16);
    r.v[4]=b2f(q.z&0xffffu); r.v[5]=b2f(q.z>>16);
    r.v[6]=b2f(q.w&0xffffu); r.v[7]=b2f(q.w>>16);
  }
  return r;
}
__device__ __forceinline__ float ld1(const void* p, size_t i, bool f32){
  return f32 ? ((const float*)p)[i] : b2f(((const u16*)p)[i]);
}
__device__ __forceinline__ float dot8(const F8& w, const float* x){
  float4 a = *(const float4*)x; float4 b = *(const float4*)(x+4);
  return w.v[0]*a.x + w.v[1]*a.y + w.v[2]*a.z + w.v[3]*a.w
       + w.v[4]*b.x + w.v[5]*b.y + w.v[6]*b.z + w.v[7]*b.w;
}

// ---------------- K1a: enc_proj[b][l][e] = sum_d W1[e][d]*imgs[b][l][d] (bf16 out) ----------------
extern "C" __global__ __launch_bounds__(256)
void k_encproj(const void* __restrict__ imgs, const void* __restrict__ W1, char* __restrict__ ws){
  __shared__ __align__(16) float sImg[16*256];
  __shared__ int sF;
  const int tid = threadIdx.x, bid = blockIdx.x;
  if (tid == 0) sF = detect_f32(imgs);
  __syncthreads();
  const bool F32 = sF != 0;
  const size_t r0 = (size_t)bid * 16;          // flat (b,l) row base
  for (int ri=0; ri<16; ri++) sImg[ri*256+tid] = ld1(imgs, (r0+ri)*256 + tid, F32);
  __syncthreads();
  float acc[16];
  #pragma unroll
  for (int ri=0; ri<16; ri++) acc[ri]=0.f;
  for (int c=0; c<32; c++){
    F8 wv = ld8(W1, (size_t)tid*256 + c*8, F32);
    #pragma unroll
    for (int ri=0; ri<16; ri++) acc[ri] += dot8(wv, sImg + ri*256 + c*8);
  }
  u16* encP = (u16*)(ws + OFF_ENCP);
  for (int ri=0; ri<16; ri++) encP[(r0+ri)*256 + tid] = f2b(acc[ri]);
}

// ---------------- K1b: gy[t][b][j] = W_ih[j][0:256] @ emb[y_t] + b_ih[j] + b_hh[j] ----------------
extern "C" __global__ __launch_bounds__(256)
void k_gatesy(const void* __restrict__ emb, const void* __restrict__ W_ih,
              const void* __restrict__ b_ih, const void* __restrict__ b_hh,
              const int* __restrict__ tgt, const void* __restrict__ imgs,
              char* __restrict__ ws){
  __shared__ __align__(16) float semb[32*256];
  __shared__ int sY[32];
  __shared__ int sF;
  const int tid = threadIdx.x, bid = blockIdx.x;
  const int b = bid >> 5, s = bid & 31;
  if (tid == 0) sF = detect_f32(imgs);
  __syncthreads();
  const bool F32 = sF != 0;
  const int r = tid >> 3, p = tid & 7, j = s*32 + r;
  float w[32];
  #pragma unroll
  for (int c=0; c<4; c++){
    F8 v = ld8(W_ih, (size_t)j*512 + p*32 + c*8, F32);
    #pragma unroll
    for (int i=0; i<8; i++) w[c*8+i] = v.v[i];
  }
  const float bias = ld1(b_ih, j, F32) + ld1(b_hh, j, F32);
  float* gy = (float*)(ws + OFF_GY);
  for (int q=0; q<4; q++){
    const int T0 = q*32;
    __syncthreads();
    if (tid < 32) sY[tid] = tgt[b*128 + T0 + tid];
    __syncthreads();
    for (int i=tid; i<32*256; i+=256){
      int tt = i>>8, e = i&255;
      semb[i] = ld1(emb, (size_t)sY[tt]*256 + e, F32);
    }
    __syncthreads();
    for (int tt=0; tt<32; tt++){
      const float* x = semb + tt*256 + p*32;
      float a = 0.f;
      #pragma unroll
      for (int i=0; i<32; i++) a += w[i]*x[i];
      a += __shfl_xor(a,1); a += __shfl_xor(a,2); a += __shfl_xor(a,4);
      if (p == 0) gy[((size_t)(T0+tt)*16 + b)*1024 + j] = a + bias;
    }
  }
}

// ---------------- K2: the recurrence. One WG per batch element; all state in LDS. ----------------
extern "C" __global__ __launch_bounds__(1024)
void k_recur(const void* __restrict__ imgs, const void* __restrict__ W_ih,
             const void* __restrict__ W_hh, const void* __restrict__ W2,
             const void* __restrict__ W3,   const void* __restrict__ beta,
             const void* __restrict__ whW,  const void* __restrict__ whb,
             const void* __restrict__ wcW,  const void* __restrict__ wcb,
             const void* __restrict__ woW,  const void* __restrict__ wob,
             char* __restrict__ ws){
  const int tid = threadIdx.x, b = blockIdx.x;
  __shared__ __align__(16) float sH[256];
  __shared__ __align__(16) float sC[256];
  __shared__ __align__(16) float sO[256];
  __shared__ __align__(16) float sHw2[256];
  __shared__ __align__(16) float sCtx[256];
  __shared__ __align__(16) float sE[256];
  __shared__ __align__(16) float sBeta[256];
  __shared__ __align__(16) float sRed[256];
  __shared__ __align__(16) float sG[1024];
  __shared__ __align__(16) float sPart[4][256];
  __shared__ int sF;
  if (tid == 0) sF = detect_f32(imgs);
  __syncthreads();
  const bool F32 = sF != 0;
  if (tid < 256) sBeta[tid] = ld1(beta, tid, F32);

  // mean_enc
  { const int lq = tid>>8, d = tid&255;
    float m = 0.f;
    for (int l=lq*64; l<lq*64+64; l++) m += ld1(imgs, ((size_t)b*256 + l)*256 + d, F32);
    sPart[lq][d] = m;
  }
  __syncthreads();
  if (tid < 256) sRed[tid] = (sPart[0][tid]+sPart[1][tid]+sPart[2][tid]+sPart[3][tid])*(1.f/256.f);
  __syncthreads();
  // init h,c,o
  { const int u = tid>>2, p = tid&3;
    float ah=0.f, ac=0.f, ao=0.f;
    #pragma unroll
    for (int c=0; c<8; c++){
      const size_t off = (size_t)u*256 + p*64 + c*8;
      const float* x = sRed + p*64 + c*8;
      ah += dot8(ld8(whW, off, F32), x);
      ac += dot8(ld8(wcW, off, F32), x);
      ao += dot8(ld8(woW, off, F32), x);
    }
    ah += __shfl_xor(ah,1); ah += __shfl_xor(ah,2);
    ac += __shfl_xor(ac,1); ac += __shfl_xor(ac,2);
    ao += __shfl_xor(ao,1); ao += __shfl_xor(ao,2);
    if (p == 0){
      sH[u] = tanhf(ah + ld1(whb, u, F32));
      sC[u] = tanhf(ac + ld1(wcb, u, F32));
      sO[u] = tanhf(ao + ld1(wob, u, F32));
    }
  }
  __syncthreads();

  const u16* encPb = (const u16*)(ws + OFF_ENCP) + (size_t)b*65536;
  const float* gy  = (const float*)(ws + OFF_GY);
  float* oAll      = (float*)(ws + OFF_OALL);

  for (int t=0; t<128; t++){
    // 1: gates (thread = gate row j); input = [emb (precomputed); o; h]
    { const int j = tid;
      float a = gy[((size_t)t*16 + b)*1024 + j];
      #pragma unroll 8
      for (int c=0; c<32; c++) a += dot8(ld8(W_ih, (size_t)j*512 + 256 + c*8, F32), sO + c*8);
      #pragma unroll 8
      for (int c=0; c<32; c++) a += dot8(ld8(W_hh, (size_t)j*256 + c*8, F32), sH + c*8);
      sG[j] = a;
    }
    __syncthreads();
    // 2: LSTM pointwise (gate order i,f,g,o)
    if (tid < 256){
      const int u = tid;
      float ig = sG[u], fg = sG[256+u], gg = sG[512+u], og = sG[768+u];
      float cn = sigm(fg)*sC[u] + sigm(ig)*tanh_f(gg);
      float hn = sigm(og)*tanh_f(cn);
      sC[u] = cn; sH[u] = hn;
    }
    __syncthreads();
    // 3: hW2[d] = (h_new @ W2^T)[d]
    { const int d = tid>>2, p = tid&3;
      float a = 0.f;
      #pragma unroll
      for (int c=0; c<8; c++) a += dot8(ld8(W2, (size_t)d*256 + p*64 + c*8, F32), sH + p*64 + c*8);
      a += __shfl_xor(a,1); a += __shfl_xor(a,2);
      if (p == 0) sHw2[d] = a;
    }
    __syncthreads();
    // 4: scores + exp (no max-sub needed: |score| <= sum|beta| ~ 2.6)
    { const int l = tid>>2, p = tid&3;
      const u16* ep = encPb + (size_t)l*256;
      float sc = 0.f;
      for (int i=0; i<64; i++){
        int d = p*64 + i;
        sc += tanh_f(b2f(ep[d]) + sHw2[d]) * sBeta[d];
      }
      sc += __shfl_xor(sc,1); sc += __shfl_xor(sc,2);
      if (p == 0) sE[l] = __expf(sc);
    }
    __syncthreads();
    // 5: exp-sum
    if (tid < 256) sRed[tid] = sE[tid];
    __syncthreads();
    for (int s2=128; s2>0; s2>>=1){ if (tid < s2) sRed[tid] += sRed[tid+s2]; __syncthreads(); }
    const float se = sRed[0];
    // 6: ctx[d] = sum_l e_l * imgs[b][l][d] / se
    { const int lq = tid>>8, d = tid&255;
      float cx = 0.f;
      for (int l=lq*64; l<lq*64+64; l++) cx += sE[l] * ld1(imgs, ((size_t)b*256 + l)*256 + d, F32);
      sPart[lq][d] = cx;
    }
    __syncthreads();
    if (tid < 256) sCtx[tid] = (sPart[0][tid]+sPart[1][tid]+sPart[2][tid]+sPart[3][tid]) / se;
    __syncthreads();
    // 7: o_new[u] = tanh(W3[u] @ [h_new; ctx])
    { const int u = tid>>2, p = tid&3;
      float a = 0.f;
      #pragma unroll
      for (int c=0; c<16; c++){
        const int k = p*128 + c*8;
        const float* x = (k < 256) ? (sH + k) : (sCtx + k - 256);
        a += dot8(ld8(W3, (size_t)u*512 + k, F32), x);
      }
      a += __shfl_xor(a,1); a += __shfl_xor(a,2);
      if (p == 0) sO[u] = tanh_f(a);
    }
    __syncthreads();
    if (tid < 256) oAll[((size_t)t*16 + b)*256 + tid] = sO[tid];
    __syncthreads();
  }
}

// ---------------- K3: logits + softmax over all (b,t); f32 output ----------------
extern "C" __global__ __launch_bounds__(256)
void k_logits(const void* __restrict__ Wout, const void* __restrict__ imgs,
              char* __restrict__ ws, float* __restrict__ out){
  __shared__ __align__(16) float sO_[256];
  __shared__ __align__(16) float sRed[256];
  __shared__ int sF;
  const int tid = threadIdx.x, bid = blockIdx.x;
  if (tid == 0) sF = detect_f32(imgs);
  __syncthreads();
  const bool F32 = sF != 0;
  const float* oAll = (const float*)(ws + OFF_OALL);
  for (int r=0; r<8; r++){
    const int q = bid*8 + r;
    const int b = q >> 7, t = q & 127;
    __syncthreads();
    sO_[tid] = oAll[((size_t)t*16 + b)*256 + tid];
    __syncthreads();
    float lg = 0.f;
    if (tid < 172){
      #pragma unroll 8
      for (int c=0; c<32; c++) lg += dot8(ld8(Wout, (size_t)tid*256 + c*8, F32), sO_ + c*8);
    }
    sRed[tid] = (tid < 172) ? lg : -1e30f;
    __syncthreads();
    for (int s2=128; s2>0; s2>>=1){ if (tid < s2) sRed[tid] = fmaxf(sRed[tid], sRed[tid+s2]); __syncthreads(); }
    const float mx = sRed[0];
    __syncthreads();
    const float ev = (tid < 172) ? __expf(lg - mx) : 0.f;
    sRed[tid] = ev;
    __syncthreads();
    for (int s2=128; s2>0; s2>>=1){ if (tid < s2) sRed[tid] += sRed[tid+s2]; __syncthreads(); }
    const float inv = 1.0f / sRed[0];
    if (tid < 172) out[((size_t)b*128 + t)*172 + tid] = ev * inv;   // f32 store
    __syncthreads();
  }
}

extern "C" void kernel_launch(void* const* d_in, const int* in_sizes, int n_in,
                              void* d_out, int out_size, void* d_ws, size_t ws_size,
                              hipStream_t stream) {
  (void)in_sizes; (void)n_in; (void)out_size; (void)ws_size;
  const void* imgs = d_in[0];
  const int*  tgt  = (const int*)d_in[1];
  const void* emb  = d_in[2];
  const void* W_ih = d_in[3];
  const void* W_hh = d_in[4];
  const void* b_ih = d_in[5];
  const void* b_hh = d_in[6];
  const void* W1   = d_in[7];
  const void* W2   = d_in[8];
  const void* W3   = d_in[9];
  const void* Wout = d_in[10];
  const void* beta = d_in[11];
  const void* whW  = d_in[12];
  const void* whb  = d_in[13];
  const void* wcW  = d_in[14];
  const void* wcb  = d_in[15];
  const void* woW  = d_in[16];
  const void* wob  = d_in[17];
  char* ws = (char*)d_ws;
  float* out = (float*)d_out;

  k_encproj<<<256, 256, 0, stream>>>(imgs, W1, ws);
  k_gatesy <<<512, 256, 0, stream>>>(emb, W_ih, b_ih, b_hh, tgt, imgs, ws);
  k_recur  <<<16, 1024, 0, stream>>>(imgs, W_ih, W_hh, W2, W3, beta,
                                     whW, whb, wcW, wcb, woW, wob, ws);
  k_logits <<<256, 256, 0, stream>>>(Wout, imgs, ws, out);
}

// Round 6
// 14778.363 us; speedup vs baseline: 1.2728x; 1.2728x over previous
//
#include <hip/hip_runtime.h>

typedef unsigned int u32;

// sizes: B=16, L=256, D=256, H=256, E=256, V=172, T=128   (all inputs f32, output f32)
// grid 256 WGs x 256 thr. g = bid&15 (batch; XCD-affine under bid%8 dispatch), w = bid>>4.
// WG (g,w) owns LSTM units u0=w*16..+16 (gate rows, W2 cols, W3 rows) and l-chunk w*16..+16.

// workspace layout (bytes); total ~2.7 MB (proven ws_size >= 12 MB in round 5)
#define OFF_BAR   0ull          // u32[16*1024]  per-group monotone counters, slot = g*1024 + t*3+ph (999 = init)
#define OFF_STH   65536ull      // f32 [2][16][256]  ping-pong h
#define OFF_STO   98304ull      // f32 [16][256]
#define OFF_PHW2  114688ull     // f32 [16][16][256]  partial h@W2^T
#define OFF_PCTX  376832ull     // f32 [16][16][256]  partial ctx
#define OFF_PSE   638976ull     // f32 [16][16]       partial exp-sums
#define OFF_OALL  643072ull     // f32 [128][16][256] o_t per step

__device__ __forceinline__ float sigm(float x){ return 1.0f/(1.0f+__expf(-x)); }
__device__ __forceinline__ float tanh_f(float x){ return 1.0f - 2.0f/(1.0f+__expf(2.0f*x)); }

struct F8 { float v[8]; };
__device__ __forceinline__ F8 ld8f(const float* q){
  F8 r; float4 a = *(const float4*)q; float4 b = *(const float4*)(q+4);
  r.v[0]=a.x;r.v[1]=a.y;r.v[2]=a.z;r.v[3]=a.w;r.v[4]=b.x;r.v[5]=b.y;r.v[6]=b.z;r.v[7]=b.w;
  return r;
}
__device__ __forceinline__ float dot8(const F8& w, const float* x){
  float4 a = *(const float4*)x; float4 b = *(const float4*)(x+4);
  return w.v[0]*a.x + w.v[1]*a.y + w.v[2]*a.z + w.v[3]*a.w
       + w.v[4]*b.x + w.v[5]*b.y + w.v[6]*b.z + w.v[7]*b.w;
}

// agent-scope (cross-XCD-coherent) 4B ops for cross-WG data
__device__ __forceinline__ float cohload(const float* p){
  u32 x = __hip_atomic_load((const u32*)p, __ATOMIC_RELAXED, __HIP_MEMORY_SCOPE_AGENT);
  float f; __builtin_memcpy(&f,&x,4); return f;
}
__device__ __forceinline__ void cohstore(float* p, float v){
  u32 x; __builtin_memcpy(&x,&v,4);
  __hip_atomic_store((u32*)p, x, __ATOMIC_RELAXED, __HIP_MEMORY_SCOPE_AGENT);
}

// group barrier: fresh monotone counter per use; arrive=atomicAdd, spin=coherent load
__device__ __forceinline__ void gbarrier(u32* cnt, u32 target){
  __threadfence();
  __syncthreads();
  if (threadIdx.x == 0){
    __hip_atomic_fetch_add(cnt, 1u, __ATOMIC_ACQ_REL, __HIP_MEMORY_SCOPE_AGENT);
    while (__hip_atomic_load(cnt, __ATOMIC_ACQUIRE, __HIP_MEMORY_SCOPE_AGENT) < target){
      __builtin_amdgcn_s_sleep(2);
    }
  }
  __syncthreads();
  __threadfence();
}

// ---------------- K0: zero barrier counters (ws is poisoned 0xAA pre-launch) ----------------
extern "C" __global__ __launch_bounds__(256)
void k_init(char* __restrict__ ws){
  u32* bar = (u32*)(ws + OFF_BAR);
  const int gt = blockIdx.x*256 + threadIdx.x;
  if (gt < 16384) bar[gt] = 0u;
}

// ---------------- K1: parallel recurrence, 16 groups x 16 WGs ----------------
extern "C" __global__ __launch_bounds__(256)
void k_main(const float* __restrict__ imgs, const int* __restrict__ tgt,
            const float* __restrict__ emb,  const float* __restrict__ W_ih,
            const float* __restrict__ W_hh, const float* __restrict__ b_ih,
            const float* __restrict__ b_hh, const float* __restrict__ W1,
            const float* __restrict__ W2,   const float* __restrict__ W3,
            const float* __restrict__ beta, const float* __restrict__ whW,
            const float* __restrict__ whb,  const float* __restrict__ wcW,
            const float* __restrict__ wcb,  const float* __restrict__ woW,
            const float* __restrict__ wob,  char* __restrict__ ws)
{
  const int tid = threadIdx.x, bid = blockIdx.x;
  const int g = bid & 15, w = bid >> 4, u0 = w*16;

  u32*   bar  = (u32*)(ws + OFF_BAR) + g*1024;
  float* stH  = (float*)(ws + OFF_STH);
  float* stO  = (float*)(ws + OFF_STO);
  float* pHW2 = (float*)(ws + OFF_PHW2);
  float* pCTX = (float*)(ws + OFF_PCTX);
  float* pSE  = (float*)(ws + OFF_PSE);
  float* oAll = (float*)(ws + OFF_OALL);

  __shared__ __align__(16) float sImg[16*256];   // own (b, l-chunk) img rows
  __shared__ __align__(16) float sEnc[16*256];   // own enc_proj rows (f32, WG-private)
  __shared__ __align__(16) float sPool[768];     // [0,256)=o  [256,512)=h  [512,768)=emb
  __shared__ __align__(16) float sHw2[256];
  __shared__ __align__(16) float sCtx[256];
  __shared__ float sBeta[256];
  __shared__ float sG[64];
  __shared__ float sHn[16];
  __shared__ float sC[16];
  __shared__ float sE[16];
  __shared__ float sE2[16];

  sBeta[tid] = beta[tid];

  // ---- setup: stage img chunk, compute own enc_proj rows (W1 row per thread) ----
  { const size_t r0 = (size_t)(g*256 + w*16);
    for (int ri=0; ri<16; ri++) sImg[ri*256+tid] = imgs[(r0+ri)*256 + tid];
    __syncthreads();
    float acc[16];
    #pragma unroll
    for (int ri=0; ri<16; ri++) acc[ri]=0.f;
    const float* w1r = W1 + (size_t)tid*256;
    for (int c=0; c<32; c++){
      F8 wv = ld8f(w1r + c*8);
      #pragma unroll
      for (int ri=0; ri<16; ri++) acc[ri] += dot8(wv, sImg + ri*256 + c*8);
    }
    for (int ri=0; ri<16; ri++) sEnc[ri*256+tid] = acc[ri];
  }
  __syncthreads();

  // ---- init states: mean_enc (per-WG redundant), own 16 units ----
  { float m = 0.f;
    for (int l=0; l<256; l++) m += imgs[((size_t)g*256 + l)*256 + tid];
    sPool[tid] = m * (1.0f/256.0f);
  }
  __syncthreads();
  { const int j = tid>>4, sub = tid&15, u = u0 + j;
    float ah=0.f, ac=0.f, ao=0.f;
    #pragma unroll
    for (int c=0; c<2; c++){
      const size_t off = (size_t)u*256 + sub*16 + c*8;
      const float* x = sPool + sub*16 + c*8;
      ah += dot8(ld8f(whW + off), x);
      ac += dot8(ld8f(wcW + off), x);
      ao += dot8(ld8f(woW + off), x);
    }
    ah += __shfl_xor(ah,1); ah += __shfl_xor(ah,2); ah += __shfl_xor(ah,4); ah += __shfl_xor(ah,8);
    ac += __shfl_xor(ac,1); ac += __shfl_xor(ac,2); ac += __shfl_xor(ac,4); ac += __shfl_xor(ac,8);
    ao += __shfl_xor(ao,1); ao += __shfl_xor(ao,2); ao += __shfl_xor(ao,4); ao += __shfl_xor(ao,8);
    if (sub == 0){
      cohstore(stH + g*256 + u, tanhf(ah + whb[u]));   // ping buffer 0
      sC[j] = tanhf(ac + wcb[u]);                       // c-state private to owner WG
      cohstore(stO + g*256 + u, tanhf(ao + wob[u]));
    }
  }
  gbarrier(bar + 999, 16);

  // ---- per-thread constants for the loop ----
  const int rl = tid>>2, p = tid&3;            // 64 gate-rows x 4 partial lanes
  const int unit = rl & 15, gate = rl >> 4;
  const int grow = gate*256 + u0 + unit;       // gate row in [4H], order i,f,g,o
  const float bsum = b_ih[grow] + b_hh[grow];
  const float* wie = W_ih + (size_t)grow*512 +       p*64;   // emb part
  const float* wio = W_ih + (size_t)grow*512 + 256 + p*64;   // o part
  const float* whh = W_hh + (size_t)grow*256 +       p*64;
  // register-preloaded W2 slice (row tid, cols u0..u0+16)
  float w2s[16];
  #pragma unroll
  for (int c=0; c<2; c++){ F8 v = ld8f(W2 + (size_t)tid*256 + u0 + c*8);
    #pragma unroll
    for (int i=0; i<8; i++) w2s[c*8+i] = v.v[i]; }
  // register-preloaded W3 slice (row u0+(tid>>4), cols (tid&15)*32..+32)
  const int j3 = tid>>4, s3 = tid&15, u3 = u0 + j3;
  float w3s[32];
  #pragma unroll
  for (int c=0; c<4; c++){ F8 v = ld8f(W3 + (size_t)u3*512 + s3*32 + c*8);
    #pragma unroll
    for (int i=0; i<8; i++) w3s[c*8+i] = v.v[i]; }
  const int* tgt_g = tgt + g*128;

  for (int t=0; t<128; t++){
    const int rdh = t&1, wrh = rdh^1;
    const int y = tgt_g[t];

    // ---- P1: stage o,h,emb; 64 gate rows; LSTM pointwise; partial h@W2^T ----
    sPool[tid]     = cohload(stO + g*256 + tid);
    sPool[256+tid] = cohload(stH + rdh*4096 + g*256 + tid);
    sPool[512+tid] = emb[(size_t)y*256 + tid];
    __syncthreads();
    { float acc = 0.f;
      const float* xe = sPool + 512 + p*64;
      const float* xo = sPool +       p*64;
      const float* xh = sPool + 256 + p*64;
      #pragma unroll
      for (int c=0; c<8; c++){
        acc += dot8(ld8f(wie + c*8), xe + c*8);
        acc += dot8(ld8f(wio + c*8), xo + c*8);
        acc += dot8(ld8f(whh + c*8), xh + c*8);
      }
      acc += __shfl_xor(acc, 1); acc += __shfl_xor(acc, 2);
      if (p == 0) sG[rl] = acc + bsum;
    }
    __syncthreads();
    if (tid < 16){
      float ig = sG[tid], fg = sG[16+tid], gg = sG[32+tid], og = sG[48+tid];
      float cn = sigm(fg)*sC[tid] + sigm(ig)*tanh_f(gg);
      float hn = sigm(og)*tanh_f(cn);
      sC[tid] = cn; sHn[tid] = hn;
      cohstore(stH + wrh*4096 + g*256 + u0 + tid, hn);
    }
    __syncthreads();
    { float s = 0.f;
      #pragma unroll
      for (int j=0; j<16; j++) s += w2s[j] * sHn[j];
      cohstore(pHW2 + (g*16+w)*256 + tid, s);
    }
    gbarrier(bar + t*3 + 0, 16);

    // ---- P2: full hW2; scores over own l-chunk; partial ctx & expsum ----
    { float s = 0.f;
      #pragma unroll
      for (int j=0; j<16; j++) s += cohload(pHW2 + (g*16+j)*256 + tid);
      sHw2[tid] = s;
    }
    __syncthreads();
    { const int li = tid>>4, sub = tid&15;
      const float* ep = sEnc + li*256;
      float sc = 0.f;
      #pragma unroll
      for (int i=0; i<16; i++){ int d = i*16 + sub; sc += tanh_f(ep[d] + sHw2[d]) * sBeta[d]; }
      sc += __shfl_xor(sc,1); sc += __shfl_xor(sc,2); sc += __shfl_xor(sc,4); sc += __shfl_xor(sc,8);
      if (sub == 0) sE[li] = __expf(sc);   // |sc| <= sum|beta| ~ 1.3, no max-sub needed
    }
    __syncthreads();
    if (tid == 0){
      float se = 0.f;
      #pragma unroll
      for (int j=0; j<16; j++) se += sE[j];
      cohstore(pSE + g*16 + w, se);
    }
    { float c = 0.f;
      #pragma unroll
      for (int li2=0; li2<16; li2++) c += sE[li2] * sImg[li2*256 + tid];
      cohstore(pCTX + (g*16+w)*256 + tid, c);
    }
    gbarrier(bar + t*3 + 1, 16);

    // ---- P3: reduce ctx; o_new = tanh(W3 @ [h_new; ctx]) ----
    if (tid < 16) sE2[tid] = cohload(pSE + g*16 + tid);
    float cd = 0.f;
    #pragma unroll
    for (int j=0; j<16; j++) cd += cohload(pCTX + (g*16+j)*256 + tid);
    sPool[tid] = cohload(stH + wrh*4096 + g*256 + tid);   // full h_new
    __syncthreads();
    { float se = 0.f;
      #pragma unroll
      for (int j=0; j<16; j++) se += sE2[j];
      sCtx[tid] = cd / se;
    }
    __syncthreads();
    { const float* xb = (s3 < 8) ? (sPool + s3*32) : (sCtx + s3*32 - 256);
      float a = 0.f;
      #pragma unroll
      for (int c=0; c<4; c++){
        float4 xa = *(const float4*)(xb + c*8); float4 xbv = *(const float4*)(xb + c*8 + 4);
        a += w3s[c*8+0]*xa.x + w3s[c*8+1]*xa.y + w3s[c*8+2]*xa.z + w3s[c*8+3]*xa.w
           + w3s[c*8+4]*xbv.x + w3s[c*8+5]*xbv.y + w3s[c*8+6]*xbv.z + w3s[c*8+7]*xbv.w;
      }
      a += __shfl_xor(a,1); a += __shfl_xor(a,2); a += __shfl_xor(a,4); a += __shfl_xor(a,8);
      if (s3 == 0){
        float o = tanh_f(a);
        cohstore(stO + g*256 + u3, o);
        oAll[((size_t)t*16 + g)*256 + u3] = o;   // plain store; read next kernel
      }
    }
    gbarrier(bar + t*3 + 2, 16);
  }
}

// ---------------- K2: logits + softmax over all (b,t); f32 output ----------------
extern "C" __global__ __launch_bounds__(256)
void k_logits(const float* __restrict__ Wout, char* __restrict__ ws, float* __restrict__ out){
  __shared__ __align__(16) float sO_[256];
  __shared__ __align__(16) float sRed[256];
  const int tid = threadIdx.x, bid = blockIdx.x;
  const float* oAll = (const float*)(ws + OFF_OALL);
  for (int r=0; r<8; r++){
    const int q = bid*8 + r;
    const int b = q >> 7, t = q & 127;
    __syncthreads();
    sO_[tid] = oAll[((size_t)t*16 + b)*256 + tid];
    __syncthreads();
    float lg = 0.f;
    if (tid < 172){
      const float* wr = Wout + (size_t)tid*256;
      #pragma unroll 8
      for (int c=0; c<32; c++) lg += dot8(ld8f(wr + c*8), sO_ + c*8);
    }
    sRed[tid] = (tid < 172) ? lg : -1e30f;
    __syncthreads();
    for (int s2=128; s2>0; s2>>=1){ if (tid < s2) sRed[tid] = fmaxf(sRed[tid], sRed[tid+s2]); __syncthreads(); }
    const float mx = sRed[0];
    __syncthreads();
    const float ev = (tid < 172) ? __expf(lg - mx) : 0.f;
    sRed[tid] = ev;
    __syncthreads();
    for (int s2=128; s2>0; s2>>=1){ if (tid < s2) sRed[tid] += sRed[tid+s2]; __syncthreads(); }
    const float inv = 1.0f / sRed[0];
    if (tid < 172) out[((size_t)b*128 + t)*172 + tid] = ev * inv;
    __syncthreads();
  }
}

extern "C" void kernel_launch(void* const* d_in, const int* in_sizes, int n_in,
                              void* d_out, int out_size, void* d_ws, size_t ws_size,
                              hipStream_t stream) {
  (void)in_sizes; (void)n_in; (void)out_size; (void)ws_size;
  char* ws = (char*)d_ws;
  k_init<<<64, 256, 0, stream>>>(ws);
  k_main<<<256, 256, 0, stream>>>(
      (const float*)d_in[0],  (const int*)d_in[1],  (const float*)d_in[2],
      (const float*)d_in[3],  (const float*)d_in[4], (const float*)d_in[5],
      (const float*)d_in[6],  (const float*)d_in[7], (const float*)d_in[8],
      (const float*)d_in[9],  (const float*)d_in[11], (const float*)d_in[12],
      (const float*)d_in[13], (const float*)d_in[14], (const float*)d_in[15],
      (const float*)d_in[16], (const float*)d_in[17], ws);
  k_logits<<<256, 256, 0, stream>>>((const float*)d_in[10], ws, (float*)d_out);
}

// Round 7
// 2811.457 us; speedup vs baseline: 6.6903x; 5.2565x over previous
//
#include <hip/hip_runtime.h>

typedef unsigned int u32;

// sizes: B=16, L=256, D=256, H=256, E=256, V=172, T=128   (all inputs f32, output f32)
// grid 256 WGs x 256 thr. g = bid&15 (batch; XCD-affine under bid%8 dispatch), w = bid>>4.
// WG (g,w) owns LSTM units u0=w*16..+16 (gate rows, W2 cols, W3 rows) and l-chunk w*16..+16.

// workspace layout (bytes); total ~2.7 MB
#define OFF_BAR   0ull          // u32[16*1024]  per-group monotone counters, slot = g*1024 + t*3+ph (999 = init)
#define OFF_STH   65536ull      // f32 [2][16][256]  ping-pong h
#define OFF_STO   98304ull      // f32 [16][256]
#define OFF_PHW2  114688ull     // f32 [16][16][256]  partial h@W2^T
#define OFF_PCTX  376832ull     // f32 [16][16][256]  partial ctx
#define OFF_PSE   638976ull     // f32 [16][16]       partial exp-sums
#define OFF_OALL  643072ull     // f32 [128][16][256] o_t per step

__device__ __forceinline__ float sigm(float x){ return 1.0f/(1.0f+__expf(-x)); }
__device__ __forceinline__ float tanh_f(float x){ return 1.0f - 2.0f/(1.0f+__expf(2.0f*x)); }

struct F8 { float v[8]; };
__device__ __forceinline__ F8 ld8f(const float* q){
  F8 r; float4 a = *(const float4*)q; float4 b = *(const float4*)(q+4);
  r.v[0]=a.x;r.v[1]=a.y;r.v[2]=a.z;r.v[3]=a.w;r.v[4]=b.x;r.v[5]=b.y;r.v[6]=b.z;r.v[7]=b.w;
  return r;
}
__device__ __forceinline__ float dot8(const F8& w, const float* x){
  float4 a = *(const float4*)x; float4 b = *(const float4*)(x+4);
  return w.v[0]*a.x + w.v[1]*a.y + w.v[2]*a.z + w.v[3]*a.w
       + w.v[4]*b.x + w.v[5]*b.y + w.v[6]*b.z + w.v[7]*b.w;
}

// agent-scope (cross-XCD-coherent) 4B ops for cross-WG data
__device__ __forceinline__ float cohload(const float* p){
  u32 x = __hip_atomic_load((const u32*)p, __ATOMIC_RELAXED, __HIP_MEMORY_SCOPE_AGENT);
  float f; __builtin_memcpy(&f,&x,4); return f;
}
__device__ __forceinline__ void cohstore(float* p, float v){
  u32 x; __builtin_memcpy(&x,&v,4);
  __hip_atomic_store((u32*)p, x, __ATOMIC_RELAXED, __HIP_MEMORY_SCOPE_AGENT);
}

// group barrier, flush-minimal lowering:
//   arrive = ONE release RMW (single wbl2), spin = RELAXED RMW polls (coherence-point
//   atomics, no cache maintenance per poll), exit = ONE acquire fence (single inv).
// Round-6 version polled with ACQUIRE (buffer_inv per poll) + 2x threadfence -> 38 us/barrier.
__device__ __forceinline__ void gbarrier(u32* cnt, u32 target){
  __syncthreads();
  if (threadIdx.x == 0){
    __hip_atomic_fetch_add(cnt, 1u, __ATOMIC_RELEASE, __HIP_MEMORY_SCOPE_AGENT);
    while (__hip_atomic_fetch_add(cnt, 0u, __ATOMIC_RELAXED, __HIP_MEMORY_SCOPE_AGENT) < target){
      __builtin_amdgcn_s_sleep(4);
    }
    __builtin_amdgcn_fence(__ATOMIC_ACQUIRE, "agent");
  }
  __syncthreads();
}

// ---------------- K0: zero barrier counters (ws is poisoned 0xAA pre-launch) ----------------
extern "C" __global__ __launch_bounds__(256)
void k_init(char* __restrict__ ws){
  u32* bar = (u32*)(ws + OFF_BAR);
  const int gt = blockIdx.x*256 + threadIdx.x;
  if (gt < 16384) bar[gt] = 0u;
}

// ---------------- K1: parallel recurrence, 16 groups x 16 WGs ----------------
extern "C" __global__ __launch_bounds__(256)
void k_main(const float* __restrict__ imgs, const int* __restrict__ tgt,
            const float* __restrict__ emb,  const float* __restrict__ W_ih,
            const float* __restrict__ W_hh, const float* __restrict__ b_ih,
            const float* __restrict__ b_hh, const float* __restrict__ W1,
            const float* __restrict__ W2,   const float* __restrict__ W3,
            const float* __restrict__ beta, const float* __restrict__ whW,
            const float* __restrict__ whb,  const float* __restrict__ wcW,
            const float* __restrict__ wcb,  const float* __restrict__ woW,
            const float* __restrict__ wob,  char* __restrict__ ws)
{
  const int tid = threadIdx.x, bid = blockIdx.x;
  const int g = bid & 15, w = bid >> 4, u0 = w*16;

  u32*   bar  = (u32*)(ws + OFF_BAR) + g*1024;
  float* stH  = (float*)(ws + OFF_STH);
  float* stO  = (float*)(ws + OFF_STO);
  float* pHW2 = (float*)(ws + OFF_PHW2);
  float* pCTX = (float*)(ws + OFF_PCTX);
  float* pSE  = (float*)(ws + OFF_PSE);
  float* oAll = (float*)(ws + OFF_OALL);

  __shared__ __align__(16) float sImg[16*256];   // own (b, l-chunk) img rows
  __shared__ __align__(16) float sEnc[16*256];   // own enc_proj rows (f32, WG-private)
  __shared__ __align__(16) float sPool[768];     // [0,256)=o  [256,512)=h  [512,768)=emb
  __shared__ __align__(16) float sHw2[256];
  __shared__ __align__(16) float sCtx[256];
  __shared__ float sBeta[256];
  __shared__ float sG[64];
  __shared__ float sHn[16];
  __shared__ float sC[16];
  __shared__ float sE[16];
  __shared__ float sE2[16];

  sBeta[tid] = beta[tid];

  // ---- setup: stage img chunk, compute own enc_proj rows (W1 row per thread) ----
  { const size_t r0 = (size_t)(g*256 + w*16);
    for (int ri=0; ri<16; ri++) sImg[ri*256+tid] = imgs[(r0+ri)*256 + tid];
    __syncthreads();
    float acc[16];
    #pragma unroll
    for (int ri=0; ri<16; ri++) acc[ri]=0.f;
    const float* w1r = W1 + (size_t)tid*256;
    for (int c=0; c<32; c++){
      F8 wv = ld8f(w1r + c*8);
      #pragma unroll
      for (int ri=0; ri<16; ri++) acc[ri] += dot8(wv, sImg + ri*256 + c*8);
    }
    for (int ri=0; ri<16; ri++) sEnc[ri*256+tid] = acc[ri];
  }
  __syncthreads();

  // ---- init states: mean_enc (per-WG redundant), own 16 units ----
  { float m = 0.f;
    for (int l=0; l<256; l++) m += imgs[((size_t)g*256 + l)*256 + tid];
    sPool[tid] = m * (1.0f/256.0f);
  }
  __syncthreads();
  { const int j = tid>>4, sub = tid&15, u = u0 + j;
    float ah=0.f, ac=0.f, ao=0.f;
    #pragma unroll
    for (int c=0; c<2; c++){
      const size_t off = (size_t)u*256 + sub*16 + c*8;
      const float* x = sPool + sub*16 + c*8;
      ah += dot8(ld8f(whW + off), x);
      ac += dot8(ld8f(wcW + off), x);
      ao += dot8(ld8f(woW + off), x);
    }
    ah += __shfl_xor(ah,1); ah += __shfl_xor(ah,2); ah += __shfl_xor(ah,4); ah += __shfl_xor(ah,8);
    ac += __shfl_xor(ac,1); ac += __shfl_xor(ac,2); ac += __shfl_xor(ac,4); ac += __shfl_xor(ac,8);
    ao += __shfl_xor(ao,1); ao += __shfl_xor(ao,2); ao += __shfl_xor(ao,4); ao += __shfl_xor(ao,8);
    if (sub == 0){
      cohstore(stH + g*256 + u, tanhf(ah + whb[u]));   // ping buffer 0
      sC[j] = tanhf(ac + wcb[u]);                       // c-state private to owner WG
      cohstore(stO + g*256 + u, tanhf(ao + wob[u]));
    }
  }
  gbarrier(bar + 999, 16);

  // ---- per-thread constants for the loop ----
  const int rl = tid>>2, p = tid&3;            // 64 gate-rows x 4 partial lanes
  const int unit = rl & 15, gate = rl >> 4;
  const int grow = gate*256 + u0 + unit;       // gate row in [4H], order i,f,g,o
  const float bsum = b_ih[grow] + b_hh[grow];
  const float* wie = W_ih + (size_t)grow*512 +       p*64;   // emb part
  const float* wio = W_ih + (size_t)grow*512 + 256 + p*64;   // o part
  const float* whh = W_hh + (size_t)grow*256 +       p*64;
  // register-preloaded W2 slice (row tid, cols u0..u0+16)
  float w2s[16];
  #pragma unroll
  for (int c=0; c<2; c++){ F8 v = ld8f(W2 + (size_t)tid*256 + u0 + c*8);
    #pragma unroll
    for (int i=0; i<8; i++) w2s[c*8+i] = v.v[i]; }
  // register-preloaded W3 slice (row u0+(tid>>4), cols (tid&15)*32..+32)
  const int j3 = tid>>4, s3 = tid&15, u3 = u0 + j3;
  float w3s[32];
  #pragma unroll
  for (int c=0; c<4; c++){ F8 v = ld8f(W3 + (size_t)u3*512 + s3*32 + c*8);
    #pragma unroll
    for (int i=0; i<8; i++) w3s[c*8+i] = v.v[i]; }
  const int* tgt_g = tgt + g*128;

  for (int t=0; t<128; t++){
    const int rdh = t&1, wrh = rdh^1;
    const int y = tgt_g[t];

    // ---- P1: stage o,h,emb; 64 gate rows; LSTM pointwise; partial h@W2^T ----
    sPool[tid]     = cohload(stO + g*256 + tid);
    sPool[256+tid] = cohload(stH + rdh*4096 + g*256 + tid);
    sPool[512+tid] = emb[(size_t)y*256 + tid];
    __syncthreads();
    { float acc = 0.f;
      const float* xe = sPool + 512 + p*64;
      const float* xo = sPool +       p*64;
      const float* xh = sPool + 256 + p*64;
      #pragma unroll
      for (int c=0; c<8; c++){
        acc += dot8(ld8f(wie + c*8), xe + c*8);
        acc += dot8(ld8f(wio + c*8), xo + c*8);
        acc += dot8(ld8f(whh + c*8), xh + c*8);
      }
      acc += __shfl_xor(acc, 1); acc += __shfl_xor(acc, 2);
      if (p == 0) sG[rl] = acc + bsum;
    }
    __syncthreads();
    if (tid < 16){
      float ig = sG[tid], fg = sG[16+tid], gg = sG[32+tid], og = sG[48+tid];
      float cn = sigm(fg)*sC[tid] + sigm(ig)*tanh_f(gg);
      float hn = sigm(og)*tanh_f(cn);
      sC[tid] = cn; sHn[tid] = hn;
      cohstore(stH + wrh*4096 + g*256 + u0 + tid, hn);
    }
    __syncthreads();
    { float s = 0.f;
      #pragma unroll
      for (int j=0; j<16; j++) s += w2s[j] * sHn[j];
      cohstore(pHW2 + (g*16+w)*256 + tid, s);
    }
    gbarrier(bar + t*3 + 0, 16);

    // ---- P2: full hW2; scores over own l-chunk; partial ctx & expsum ----
    { float s = 0.f;
      #pragma unroll
      for (int j=0; j<16; j++) s += cohload(pHW2 + (g*16+j)*256 + tid);
      sHw2[tid] = s;
    }
    __syncthreads();
    { const int li = tid>>4, sub = tid&15;
      const float* ep = sEnc + li*256;
      float sc = 0.f;
      #pragma unroll
      for (int i=0; i<16; i++){ int d = i*16 + sub; sc += tanh_f(ep[d] + sHw2[d]) * sBeta[d]; }
      sc += __shfl_xor(sc,1); sc += __shfl_xor(sc,2); sc += __shfl_xor(sc,4); sc += __shfl_xor(sc,8);
      if (sub == 0) sE[li] = __expf(sc);   // |sc| <= sum|beta| ~ 1.3, no max-sub needed
    }
    __syncthreads();
    if (tid == 0){
      float se = 0.f;
      #pragma unroll
      for (int j=0; j<16; j++) se += sE[j];
      cohstore(pSE + g*16 + w, se);
    }
    { float c = 0.f;
      #pragma unroll
      for (int li2=0; li2<16; li2++) c += sE[li2] * sImg[li2*256 + tid];
      cohstore(pCTX + (g*16+w)*256 + tid, c);
    }
    gbarrier(bar + t*3 + 1, 16);

    // ---- P3: reduce ctx; o_new = tanh(W3 @ [h_new; ctx]) ----
    if (tid < 16) sE2[tid] = cohload(pSE + g*16 + tid);
    float cd = 0.f;
    #pragma unroll
    for (int j=0; j<16; j++) cd += cohload(pCTX + (g*16+j)*256 + tid);
    sPool[tid] = cohload(stH + wrh*4096 + g*256 + tid);   // full h_new
    __syncthreads();
    { float se = 0.f;
      #pragma unroll
      for (int j=0; j<16; j++) se += sE2[j];
      sCtx[tid] = cd / se;
    }
    __syncthreads();
    { const float* xb = (s3 < 8) ? (sPool + s3*32) : (sCtx + s3*32 - 256);
      float a = 0.f;
      #pragma unroll
      for (int c=0; c<4; c++){
        float4 xa = *(const float4*)(xb + c*8); float4 xbv = *(const float4*)(xb + c*8 + 4);
        a += w3s[c*8+0]*xa.x + w3s[c*8+1]*xa.y + w3s[c*8+2]*xa.z + w3s[c*8+3]*xa.w
           + w3s[c*8+4]*xbv.x + w3s[c*8+5]*xbv.y + w3s[c*8+6]*xbv.z + w3s[c*8+7]*xbv.w;
      }
      a += __shfl_xor(a,1); a += __shfl_xor(a,2); a += __shfl_xor(a,4); a += __shfl_xor(a,8);
      if (s3 == 0){
        float o = tanh_f(a);
        cohstore(stO + g*256 + u3, o);
        oAll[((size_t)t*16 + g)*256 + u3] = o;   // plain store; read next kernel
      }
    }
    gbarrier(bar + t*3 + 2, 16);
  }
}

// ---------------- K2: logits + softmax over all (b,t); f32 output ----------------
extern "C" __global__ __launch_bounds__(256)
void k_logits(const float* __restrict__ Wout, char* __restrict__ ws, float* __restrict__ out){
  __shared__ __align__(16) float sO_[256];
  __shared__ __align__(16) float sRed[256];
  const int tid = threadIdx.x, bid = blockIdx.x;
  const float* oAll = (const float*)(ws + OFF_OALL);
  for (int r=0; r<8; r++){
    const int q = bid*8 + r;
    const int b = q >> 7, t = q & 127;
    __syncthreads();
    sO_[tid] = oAll[((size_t)t*16 + b)*256 + tid];
    __syncthreads();
    float lg = 0.f;
    if (tid < 172){
      const float* wr = Wout + (size_t)tid*256;
      #pragma unroll 8
      for (int c=0; c<32; c++) lg += dot8(ld8f(wr + c*8), sO_ + c*8);
    }
    sRed[tid] = (tid < 172) ? lg : -1e30f;
    __syncthreads();
    for (int s2=128; s2>0; s2>>=1){ if (tid < s2) sRed[tid] = fmaxf(sRed[tid], sRed[tid+s2]); __syncthreads(); }
    const float mx = sRed[0];
    __syncthreads();
    const float ev = (tid < 172) ? __expf(lg - mx) : 0.f;
    sRed[tid] = ev;
    __syncthreads();
    for (int s2=128; s2>0; s2>>=1){ if (tid < s2) sRed[tid] += sRed[tid+s2]; __syncthreads(); }
    const float inv = 1.0f / sRed[0];
    if (tid < 172) out[((size_t)b*128 + t)*172 + tid] = ev * inv;
    __syncthreads();
  }
}

extern "C" void kernel_launch(void* const* d_in, const int* in_sizes, int n_in,
                              void* d_out, int out_size, void* d_ws, size_t ws_size,
                              hipStream_t stream) {
  (void)in_sizes; (void)n_in; (void)out_size; (void)ws_size;
  char* ws = (char*)d_ws;
  k_init<<<64, 256, 0, stream>>>(ws);
  k_main<<<256, 256, 0, stream>>>(
      (const float*)d_in[0],  (const int*)d_in[1],  (const float*)d_in[2],
      (const float*)d_in[3],  (const float*)d_in[4], (const float*)d_in[5],
      (const float*)d_in[6],  (const float*)d_in[7], (const float*)d_in[8],
      (const float*)d_in[9],  (const float*)d_in[11], (const float*)d_in[12],
      (const float*)d_in[13], (const float*)d_in[14], (const float*)d_in[15],
      (const float*)d_in[16], (const float*)d_in[17], ws);
  k_logits<<<256, 256, 0, stream>>>((const float*)d_in[10], ws, (float*)d_out);
}